// Round 6
// baseline (728.911 us; speedup 1.0000x reference)
//
#include <hip/hip_runtime.h>
#include <math.h>

#define NUM_AGENTS 256
#define HIDDEN 1024
#define RANK 32
#define NTOK 8192
#define SPLITS 8
#define RANGE (NTOK / SPLITS)   // 1024 tokens per range-split
#define TBATCH 4
#define ALPHA_MAX 5.0f
#define LN_EPS 1e-5f

// Grid: 256 agents x 8 token-range splits = 2048 blocks, 256 threads.
// __launch_bounds__(256,4): ~128 VGPR cap so the compiler can keep 8 float4
// loads in flight (R2-R5 ran at 52-64 VGPRs -> serialized loads, ~15us/block
// critical path). Loads are hand-batched: 8 float4 into regs, then FMA.
__global__ __launch_bounds__(256, 4) void div_inject_kernel(
    const float* __restrict__ hglob,
    const float* __restrict__ log_alpha,
    const float* __restrict__ gamma,
    const float* __restrict__ beta,
    const float* __restrict__ U,
    const float* __restrict__ V,
    const int* __restrict__ ids,
    float* __restrict__ out)
{
    __shared__ unsigned short toklist[RANGE];               // 2 KB
    __shared__ int tokcount;
    __shared__ __align__(16) float Hs[TBATCH][HIDDEN];      // 16 KB
    __shared__ __align__(16) float red[4][TBATCH][RANK];    // 2 KB
    __shared__ float inter[TBATCH][RANK];                   // 0.5 KB
    __shared__ float wred[4][2][TBATCH];
    __shared__ float stat_mean[TBATCH], stat_rstd[TBATCH];

    const int t = threadIdx.x;
    const int agent = blockIdx.x & (NUM_AGENTS - 1);
    const int split = blockIdx.x >> 8;
    const int base = split * RANGE;

    if (t == 0) tokcount = 0;
    __syncthreads();

    // ---- collect this agent's tokens within our disjoint range ----
    for (int i = t; i < RANGE; i += 256) {
        int idx = base + i;
        int a = ids[idx] & (NUM_AGENTS - 1);
        if (a == agent) {
            int pos = atomicAdd(&tokcount, 1);
            toklist[pos] = (unsigned short)idx;
        }
    }
    __syncthreads();
    const int cnt = tokcount;
    if (cnt == 0) return;

    const float alpha = fminf(expf(log_alpha[0]), ALPHA_MAX);

    const float* Ua = U + (size_t)agent * HIDDEN * RANK;
    const float* Va = V + (size_t)agent * RANK * HIDDEN;

    const int r4 = (t & 7) * 4;   // rank quad: 0,4,...,28
    const int ks = t >> 3;        // k-slice 0..31 (hh = ks + 32*j)
    const int c  = t * 4;         // this thread's 4 output columns
    const int wave = t >> 6, lane = t & 63;

    const float4 gv = *(const float4*)(gamma + c);
    const float4 bv = *(const float4*)(beta + c);

    for (int g = 0; g < cnt; g += TBATCH) {
        const int nm = min(TBATCH, cnt - g);
        int tk[TBATCH];
        #pragma unroll
        for (int m = 0; m < TBATCH; ++m)
            tk[m] = (int)toklist[g + min(m, nm - 1)];   // pad by replication

        // ---- stage TBATCH h rows into LDS (f32) ----
        float4 hv[TBATCH];
        #pragma unroll
        for (int m = 0; m < TBATCH; ++m)
            hv[m] = *(const float4*)(hglob + (size_t)tk[m] * HIDDEN + c);
        #pragma unroll
        for (int m = 0; m < TBATCH; ++m)
            *(float4*)(&Hs[m][c]) = hv[m];
        __syncthreads();

        // ---- phase 2: inter[m][r] = sum_hh Hs[m][hh] * U[hh][r] ----
        // hand-batched: 8 float4 U loads in flight, then FMA
        float4 acc[TBATCH];
        #pragma unroll
        for (int m = 0; m < TBATCH; ++m) acc[m] = make_float4(0.f, 0.f, 0.f, 0.f);
        #pragma unroll
        for (int j0 = 0; j0 < 32; j0 += 8) {
            float4 u[8];
            #pragma unroll
            for (int j = 0; j < 8; ++j) {
                int hh = ks + 32 * (j0 + j);
                u[j] = *(const float4*)(Ua + hh * RANK + r4);
            }
            float hb[8][TBATCH];
            #pragma unroll
            for (int j = 0; j < 8; ++j) {
                int hh = ks + 32 * (j0 + j);
                #pragma unroll
                for (int m = 0; m < TBATCH; ++m) hb[j][m] = Hs[m][hh];
            }
            #pragma unroll
            for (int j = 0; j < 8; ++j) {
                #pragma unroll
                for (int m = 0; m < TBATCH; ++m) {
                    acc[m].x += hb[j][m] * u[j].x;
                    acc[m].y += hb[j][m] * u[j].y;
                    acc[m].z += hb[j][m] * u[j].z;
                    acc[m].w += hb[j][m] * u[j].w;
                }
            }
        }
        // reduce over the 8 k-slices within each wave
        #pragma unroll
        for (int off = 8; off <= 32; off <<= 1) {
            #pragma unroll
            for (int m = 0; m < TBATCH; ++m) {
                acc[m].x += __shfl_xor(acc[m].x, off, 64);
                acc[m].y += __shfl_xor(acc[m].y, off, 64);
                acc[m].z += __shfl_xor(acc[m].z, off, 64);
                acc[m].w += __shfl_xor(acc[m].w, off, 64);
            }
        }
        if (lane < 8) {
            #pragma unroll
            for (int m = 0; m < TBATCH; ++m)
                *(float4*)(&red[wave][m][r4]) = acc[m];
        }
        __syncthreads();
        if (t < TBATCH * RANK) {
            int m = t >> 5, rr = t & 31;
            inter[m][rr] = red[0][m][rr] + red[1][m][rr] + red[2][m][rr] + red[3][m][rr];
        }
        __syncthreads();

        // ---- phase 3: pert[m][c..c+3] = sum_r inter[m][r] * V[r][c..c+3] ----
        float4 p[TBATCH];
        #pragma unroll
        for (int m = 0; m < TBATCH; ++m) p[m] = make_float4(0.f, 0.f, 0.f, 0.f);
        #pragma unroll
        for (int r0 = 0; r0 < RANK; r0 += 8) {
            float4 v[8];
            #pragma unroll
            for (int j = 0; j < 8; ++j)
                v[j] = *(const float4*)(Va + (r0 + j) * HIDDEN + c);
            #pragma unroll
            for (int j = 0; j < 8; ++j) {
                #pragma unroll
                for (int m = 0; m < TBATCH; ++m) {
                    float ir = inter[m][r0 + j];
                    p[m].x += ir * v[j].x;
                    p[m].y += ir * v[j].y;
                    p[m].z += ir * v[j].z;
                    p[m].w += ir * v[j].w;
                }
            }
        }

        // ---- d = h + alpha*pert; batched LN stats ----
        float4 dmv[TBATCH];
        float s[TBATCH], q[TBATCH];
        #pragma unroll
        for (int m = 0; m < TBATCH; ++m) {
            float4 d;
            d.x = hv[m].x + alpha * p[m].x;
            d.y = hv[m].y + alpha * p[m].y;
            d.z = hv[m].z + alpha * p[m].z;
            d.w = hv[m].w + alpha * p[m].w;
            dmv[m] = d;
            s[m] = d.x + d.y + d.z + d.w;
            q[m] = d.x * d.x + d.y * d.y + d.z * d.z + d.w * d.w;
        }
        #pragma unroll
        for (int off = 32; off > 0; off >>= 1) {
            #pragma unroll
            for (int m = 0; m < TBATCH; ++m) {
                s[m] += __shfl_xor(s[m], off, 64);
                q[m] += __shfl_xor(q[m], off, 64);
            }
        }
        if (lane < TBATCH)               wred[wave][0][lane] = s[lane];
        else if (lane < 2 * TBATCH)      wred[wave][1][lane - TBATCH] = q[lane - TBATCH];
        __syncthreads();
        if (t < TBATCH) {
            float S = wred[0][0][t] + wred[1][0][t] + wred[2][0][t] + wred[3][0][t];
            float Q = wred[0][1][t] + wred[1][1][t] + wred[2][1][t] + wred[3][1][t];
            float mean = S * (1.0f / HIDDEN);
            float var  = Q * (1.0f / HIDDEN) - mean * mean;
            stat_mean[t] = mean;
            stat_rstd[t] = rsqrtf(var + LN_EPS);
        }
        __syncthreads();

        // ---- normalize + write ----
        for (int m = 0; m < nm; ++m) {
            float mean = stat_mean[m], rstd = stat_rstd[m];
            float4 d = dmv[m];
            float4 o;
            o.x = (d.x - mean) * rstd * gv.x + bv.x;
            o.y = (d.y - mean) * rstd * gv.y + bv.y;
            o.z = (d.z - mean) * rstd * gv.z + bv.z;
            o.w = (d.w - mean) * rstd * gv.w + bv.w;
            *(float4*)(out + (size_t)tk[m] * HIDDEN + c) = o;
        }
        __syncthreads();   // protect Hs/red/inter before next group
    }
}

extern "C" void kernel_launch(void* const* d_in, const int* in_sizes, int n_in,
                              void* d_out, int out_size, void* d_ws, size_t ws_size,
                              hipStream_t stream) {
    const float* h     = (const float*)d_in[0];
    const float* la    = (const float*)d_in[1];
    const float* gamma = (const float*)d_in[2];
    const float* beta  = (const float*)d_in[3];
    const float* U     = (const float*)d_in[4];
    const float* V     = (const float*)d_in[5];
    const int* ids     = (const int*)d_in[6];
    float* out         = (float*)d_out;

    div_inject_kernel<<<NUM_AGENTS * SPLITS, 256, 0, stream>>>(
        h, la, gamma, beta, U, V, ids, out);
}

// Round 7
// 251.970 us; speedup vs baseline: 2.8929x; 2.8929x over previous
//
#include <hip/hip_runtime.h>
#include <math.h>

#define NUM_AGENTS 256
#define HIDDEN 1024
#define RANK 32
#define NTOK 8192
#define SPLITS 2
#define RANGE (NTOK / SPLITS)   // 4096 tokens per range-split
#define TBATCH 8
#define ALPHA_MAX 5.0f
#define LN_EPS 1e-5f

// Grid: 256 agents x 2 token-range splits = 512 blocks, 256 threads.
// TBATCH=8 tokens per group: 32 FMAs per float4 U/V load (2x R4) and half the
// per-block U/V cache re-reads of SPLITS=8. No register staging arrays
// (R6's hand-batching spilled: 1.9 GB scratch traffic at VGPR=64).
__global__ __launch_bounds__(256) void div_inject_kernel(
    const float* __restrict__ hglob,
    const float* __restrict__ log_alpha,
    const float* __restrict__ gamma,
    const float* __restrict__ beta,
    const float* __restrict__ U,
    const float* __restrict__ V,
    const int* __restrict__ ids,
    float* __restrict__ out)
{
    __shared__ unsigned short toklist[RANGE];               // 8 KB
    __shared__ int tokcount;
    __shared__ __align__(16) float Hs[TBATCH][HIDDEN];      // 32 KB
    __shared__ __align__(16) float red[4][TBATCH][RANK];    // 4 KB
    __shared__ float inter[TBATCH][RANK];                   // 1 KB
    __shared__ float wred[4][2][TBATCH];
    __shared__ float stat_mean[TBATCH], stat_rstd[TBATCH];

    const int t = threadIdx.x;
    const int agent = blockIdx.x & (NUM_AGENTS - 1);
    const int split = blockIdx.x >> 8;
    const int base = split * RANGE;

    if (t == 0) tokcount = 0;
    __syncthreads();

    // ---- collect this agent's tokens within our disjoint range ----
    for (int i = t; i < RANGE; i += 256) {
        int idx = base + i;
        int a = ids[idx] & (NUM_AGENTS - 1);
        if (a == agent) {
            int pos = atomicAdd(&tokcount, 1);
            toklist[pos] = (unsigned short)idx;
        }
    }
    __syncthreads();
    const int cnt = tokcount;
    if (cnt == 0) return;

    const float alpha = fminf(expf(log_alpha[0]), ALPHA_MAX);

    const float* Ua = U + (size_t)agent * HIDDEN * RANK;
    const float* Va = V + (size_t)agent * RANK * HIDDEN;

    const int r4 = (t & 7) * 4;   // rank quad: 0,4,...,28
    const int ks = t >> 3;        // k-slice 0..31 (hh = ks + 32*j)
    const int c  = t * 4;         // this thread's 4 output columns
    const int wave = t >> 6, lane = t & 63;

    const float4 gv = *(const float4*)(gamma + c);
    const float4 bv = *(const float4*)(beta + c);

    for (int g = 0; g < cnt; g += TBATCH) {
        const int nm = min(TBATCH, cnt - g);
        int tk[TBATCH];
        #pragma unroll
        for (int m = 0; m < TBATCH; ++m)
            tk[m] = (int)toklist[g + min(m, nm - 1)];   // pad by replication

        // ---- stage TBATCH h rows into LDS (f32) ----
        #pragma unroll
        for (int m = 0; m < TBATCH; ++m)
            *(float4*)(&Hs[m][c]) = *(const float4*)(hglob + (size_t)tk[m] * HIDDEN + c);
        __syncthreads();

        // ---- phase 2: inter[m][r] = sum_hh Hs[m][hh] * U[hh][r] ----
        float4 acc[TBATCH];
        #pragma unroll
        for (int m = 0; m < TBATCH; ++m) acc[m] = make_float4(0.f, 0.f, 0.f, 0.f);
        #pragma unroll 8
        for (int j = 0; j < 32; ++j) {
            int hh = ks + 32 * j;
            float4 u = *(const float4*)(Ua + hh * RANK + r4);
            #pragma unroll
            for (int m = 0; m < TBATCH; ++m) {
                float hvv = Hs[m][hh];
                acc[m].x += hvv * u.x;
                acc[m].y += hvv * u.y;
                acc[m].z += hvv * u.z;
                acc[m].w += hvv * u.w;
            }
        }
        // reduce over the 8 k-slices within each wave (lane bits 3..5)
        #pragma unroll
        for (int off = 8; off <= 32; off <<= 1) {
            #pragma unroll
            for (int m = 0; m < TBATCH; ++m) {
                acc[m].x += __shfl_xor(acc[m].x, off, 64);
                acc[m].y += __shfl_xor(acc[m].y, off, 64);
                acc[m].z += __shfl_xor(acc[m].z, off, 64);
                acc[m].w += __shfl_xor(acc[m].w, off, 64);
            }
        }
        if (lane < 8) {
            #pragma unroll
            for (int m = 0; m < TBATCH; ++m)
                *(float4*)(&red[wave][m][r4]) = acc[m];
        }
        __syncthreads();
        {   // t covers all TBATCH*RANK = 256 entries
            int m = t >> 5, rr = t & 31;
            inter[m][rr] = red[0][m][rr] + red[1][m][rr] + red[2][m][rr] + red[3][m][rr];
        }
        __syncthreads();

        // ---- phase 3: p[m] = sum_r inter[m][r] * V[r][c..c+3] ----
        float4 p[TBATCH];
        #pragma unroll
        for (int m = 0; m < TBATCH; ++m) p[m] = make_float4(0.f, 0.f, 0.f, 0.f);
        #pragma unroll 8
        for (int r = 0; r < RANK; ++r) {
            float4 v = *(const float4*)(Va + r * HIDDEN + c);
            #pragma unroll
            for (int m = 0; m < TBATCH; ++m) {
                float ir = inter[m][r];
                p[m].x += ir * v.x;
                p[m].y += ir * v.y;
                p[m].z += ir * v.z;
                p[m].w += ir * v.w;
            }
        }

        // ---- d = h + alpha*pert (reuse p for d); batched LN stats ----
        float s[TBATCH], q[TBATCH];
        #pragma unroll
        for (int m = 0; m < TBATCH; ++m) {
            float4 hv = *(const float4*)(&Hs[m][c]);
            float4 d;
            d.x = hv.x + alpha * p[m].x;
            d.y = hv.y + alpha * p[m].y;
            d.z = hv.z + alpha * p[m].z;
            d.w = hv.w + alpha * p[m].w;
            p[m] = d;
            s[m] = d.x + d.y + d.z + d.w;
            q[m] = d.x * d.x + d.y * d.y + d.z * d.z + d.w * d.w;
        }
        #pragma unroll
        for (int off = 32; off > 0; off >>= 1) {
            #pragma unroll
            for (int m = 0; m < TBATCH; ++m) {
                s[m] += __shfl_xor(s[m], off, 64);
                q[m] += __shfl_xor(q[m], off, 64);
            }
        }
        if (lane < TBATCH)               wred[wave][0][lane] = s[lane];
        else if (lane < 2 * TBATCH)      wred[wave][1][lane - TBATCH] = q[lane - TBATCH];
        __syncthreads();
        if (t < TBATCH) {
            float S = wred[0][0][t] + wred[1][0][t] + wred[2][0][t] + wred[3][0][t];
            float Q = wred[0][1][t] + wred[1][1][t] + wred[2][1][t] + wred[3][1][t];
            float mean = S * (1.0f / HIDDEN);
            float var  = Q * (1.0f / HIDDEN) - mean * mean;
            stat_mean[t] = mean;
            stat_rstd[t] = rsqrtf(var + LN_EPS);
        }
        __syncthreads();

        // ---- normalize + write ----
        for (int m = 0; m < nm; ++m) {
            float mean = stat_mean[m], rstd = stat_rstd[m];
            float4 d = p[m];
            float4 o;
            o.x = (d.x - mean) * rstd * gv.x + bv.x;
            o.y = (d.y - mean) * rstd * gv.y + bv.y;
            o.z = (d.z - mean) * rstd * gv.z + bv.z;
            o.w = (d.w - mean) * rstd * gv.w + bv.w;
            *(float4*)(out + (size_t)tk[m] * HIDDEN + c) = o;
        }
        __syncthreads();   // protect Hs/red/inter before next group
    }
}

extern "C" void kernel_launch(void* const* d_in, const int* in_sizes, int n_in,
                              void* d_out, int out_size, void* d_ws, size_t ws_size,
                              hipStream_t stream) {
    const float* h     = (const float*)d_in[0];
    const float* la    = (const float*)d_in[1];
    const float* gamma = (const float*)d_in[2];
    const float* beta  = (const float*)d_in[3];
    const float* U     = (const float*)d_in[4];
    const float* V     = (const float*)d_in[5];
    const int* ids     = (const int*)d_in[6];
    float* out         = (float*)d_out;

    div_inject_kernel<<<NUM_AGENTS * SPLITS, 256, 0, stream>>>(
        h, la, gamma, beta, U, V, ids, out);
}